// Round 2
// baseline (491.230 us; speedup 1.0000x reference)
//
#include <hip/hip_runtime.h>

// Problem constants (from reference): B rays, SC=64 coarse dists, 63 weights,
// SF=128 fine samples, output = sort(concat(fine, coarse)) = 192 per ray.
constexpr int SC  = 64;
constexpr int SW  = 63;
constexpr int SF  = 128;
constexpr int ON  = 192;
constexpr int RPB = 4;   // rays per block: 1 wave (64 lanes) per ray

__global__ __launch_bounds__(256) void nerf_resample_kernel(
    const float* __restrict__ g_dists,
    const float* __restrict__ g_weights,
    const float* __restrict__ g_rands,
    float* __restrict__ g_out,
    int B)
{
    __shared__ float s_cdf[RPB][SC];
    __shared__ float s_d  [RPB][SC];
    __shared__ float s_smp[RPB][SF];
    __shared__ float s_out[RPB][ON];

    const int wv   = threadIdx.x >> 6;
    const int lane = threadIdx.x & 63;
    int ray = blockIdx.x * RPB + wv;
    if (ray >= B) ray = B - 1;          // duplicate last ray if grid overshoots (benign)

    float* cdf  = s_cdf[wv];
    float* sd   = s_d[wv];
    float* ssm  = s_smp[wv];
    float* sout = s_out[wv];

    // ---- load coarse dists (sorted), one per lane, coalesced
    const float dv = g_dists[ray * SC + lane];
    sd[lane] = dv;

    // ---- weights -> normalized CDF via wave prefix-sum
    float w = (lane < SW) ? (g_weights[ray * SW + lane] + 0.01f) : 0.0f;
    float ps = w;
#pragma unroll
    for (int off = 1; off < 64; off <<= 1) {
        float n = __shfl_up(ps, off);
        if (lane >= off) ps += n;
    }
    const float total = __shfl(ps, 62);   // inclusive sum at lane 62 == sum of all 63
    const float inv   = 1.0f / total;
    if (lane == 63) cdf[0] = 0.0f;        // cdf[0] = 0
    else            cdf[lane + 1] = ps * inv;   // cdf[1..63]

    // ---- load 2 uniform rands per lane (coalesced)
    const float u0 = g_rands[ray * SF + lane];
    const float u1 = g_rands[ray * SF + 64 + lane];

    __syncthreads();   // cdf + sd visible

    // ---- searchsorted(cdf, u, side='right'): ids = #{cdf <= u}, branchless
    // 6-step binary count over 64 entries; result in [1,63] (cdf[0]=0 <= u,
    // and clamp-at-63 only differs from the reference in the u>cdf[63] ulp
    // corner where both produce ~dists[63]).
    int i0 = 0, i1 = 0;
#pragma unroll
    for (int st = 32; st >= 1; st >>= 1) {
        i0 += (cdf[i0 + st - 1] <= u0) ? st : 0;
        i1 += (cdf[i1 + st - 1] <= u1) ? st : 0;
    }

    float v0, v1;
    {
        const float c0 = cdf[i0 - 1], c1 = cdf[i0];
        const float a0 = sd[i0 - 1],  a1 = sd[i0];
        float den = c1 - c0;
        if (den < 1e-5f) den = 1.0f;
        v0 = a0 + ((u0 - c0) / den) * (a1 - a0);
    }
    {
        const float c0 = cdf[i1 - 1], c1 = cdf[i1];
        const float a0 = sd[i1 - 1],  a1 = sd[i1];
        float den = c1 - c0;
        if (den < 1e-5f) den = 1.0f;
        v1 = a0 + ((u1 - c0) / den) * (a1 - a0);
    }

    // ---- bitonic sort of the 128 fine samples, fully in registers.
    // Element layout: e0 = lane holds v0, e1 = lane+64 holds v1.
#pragma unroll
    for (int k = 2; k <= 128; k <<= 1) {
        if (k == 128) {   // j = 64 substep: partner is the other register, up for all e<128
            const float lo = fminf(v0, v1), hi = fmaxf(v0, v1);
            v0 = lo; v1 = hi;
        }
#pragma unroll
        for (int j = ((k >> 1) > 32 ? 32 : (k >> 1)); j >= 1; j >>= 1) {
            const float p0 = __shfl_xor(v0, j);
            const float p1 = __shfl_xor(v1, j);
            const bool low = (lane & j) == 0;              // lower index of the pair
            const bool up0 = ((lane      ) & k) == 0;      // direction for e0
            const bool up1 = ((lane + 64) & k) == 0;       // direction for e1
            v0 = (low == up0) ? fminf(v0, p0) : fmaxf(v0, p0);
            v1 = (low == up1) ? fminf(v1, p1) : fmaxf(v1, p1);
        }
    }

    // sorted: ssm[0..63] = v0 by lane, ssm[64..127] = v1 by lane
    ssm[lane]      = v0;
    ssm[64 + lane] = v1;
    __syncthreads();

    // ---- merge-by-rank into 192 slots.
    // sample i -> i + #{d < s}  (strict);  dist j -> j + #{s <= d}.
    // Ties: samples precede dists -> bijection over [0,192).
    int r0 = 0, r1 = 0;
#pragma unroll
    for (int st = 32; st >= 1; st >>= 1) {
        r0 += (sd[r0 + st - 1] < v0) ? st : 0;
        r1 += (sd[r1 + st - 1] < v1) ? st : 0;
    }
    r0 += (sd[63] < v0) ? 1 : 0;   // count can be 64 (sample past last dist)
    r1 += (sd[63] < v1) ? 1 : 0;

    int rd = 0;
#pragma unroll
    for (int st = 64; st >= 1; st >>= 1) {
        rd += (ssm[rd + st - 1] <= dv) ? st : 0;
    }
    rd += (ssm[127] <= dv) ? 1 : 0;  // count can be 128 (dist past last sample)

    sout[lane + r0]      = v0;
    sout[64 + lane + r1] = v1;
    sout[lane + rd]      = dv;
    __syncthreads();

    // ---- coalesced store of the 192 sorted values
    const int ob = ray * ON;
    g_out[ob + lane]        = sout[lane];
    g_out[ob + 64  + lane]  = sout[64 + lane];
    g_out[ob + 128 + lane]  = sout[128 + lane];
}

extern "C" void kernel_launch(void* const* d_in, const int* in_sizes, int n_in,
                              void* d_out, int out_size, void* d_ws, size_t ws_size,
                              hipStream_t stream) {
    const float* g_dists   = (const float*)d_in[0];
    const float* g_weights = (const float*)d_in[1];
    const float* g_rands   = (const float*)d_in[2];
    float* g_out = (float*)d_out;
    const int B = in_sizes[0] / SC;
    const int nblocks = (B + RPB - 1) / RPB;
    nerf_resample_kernel<<<nblocks, 256, 0, stream>>>(g_dists, g_weights, g_rands, g_out, B);
}